// Round 4
// baseline (118.494 us; speedup 1.0000x reference)
//
#include <hip/hip_runtime.h>

#define HH 20
#define WW 20

typedef __bf16  bf16x8 __attribute__((ext_vector_type(8)));
typedef float   f32x4  __attribute__((ext_vector_type(4)));
typedef float   f32x4u __attribute__((ext_vector_type(4), aligned(4)));

// ---- prepack W: k' = r*8 + ni reorder, hi/lo split, K padded 72->96 ----
// ws: Bh[256][96] bf16, Bl[256][96] bf16
__global__ void prepack_w_kernel(const float* __restrict__ Wt, __bf16* __restrict__ bp) {
    int idx = blockIdx.x * 256 + threadIdx.x;     // 24576 total
    int oc = idx / 96, k = idx % 96;
    int r = k >> 3, ni = k & 7;
    float v = (r < 9) ? Wt[oc * 72 + ni * 9 + r] : 0.f;
    __bf16 hi = (__bf16)v;
    bp[idx]         = hi;
    bp[24576 + idx] = (__bf16)(v - (float)hi);
}

// ---- fused conv + routing ----
// region (18432 B) lifetimes:
//   phase1 stage/conv : A_hi[32][96], A_lo[32][96] bf16   (12288 B)
//   phase2 transpose  : per-wave buf f32[32][36] at Rf + wv*1152 (4*4608 B)
//   phase3 routing    : route_T f32[32][36] @Rf, act_lds @Rf+1152, logits f32[32][37] @Rf+1416
__global__ __launch_bounds__(256, 6)
void caps_mfma3_kernel(const float* __restrict__ x,
                       const __bf16* __restrict__ bp,
                       const float* __restrict__ bias,
                       float* __restrict__ out) {
    __shared__ __align__(16) unsigned char region[18432];
    __bf16* A_hi = (__bf16*)region;                     // [32][96]
    __bf16* A_lo = (__bf16*)(region + 6144);            // [32][96]
    float*  Rf   = (float*)region;
    float*  act_lds = Rf + 1152;                        // [256]
    float (*logits)[37]  = (float (*)[37])(Rf + 1416);  // [32][37]
    float (*route_T)[36] = (float (*)[36])Rf;           // [co][ci]

    const int t  = threadIdx.x;
    const int wv = t >> 6;
    const int lr = t & 15;
    const int lg = (t >> 4) & 3;

    // XCD-bijective swizzle: contiguous bi chunk per XCD (6400 % 8 == 0)
    const int bi  = (blockIdx.x & 7) * 800 + (blockIdx.x >> 3);
    const int b   = bi / 400;
    const int rem = bi % 400;
    const int h   = rem / 20;
    const int w   = rem % 20;

    // ---- zero k' pad [72,96): 12 u32 per ci per array ----
#pragma unroll
    for (int e = t; e < 384; e += 256) {
        int ci = e / 12, j = e % 12;
        ((unsigned int*)(A_hi + ci * 96 + 72))[j] = 0u;
        ((unsigned int*)(A_lo + ci * 96 + 72))[j] = 0u;
    }

    // ---- stage x patch (split bf16), k' = (hr*3+kw)*8 + ni ----
    const int wlo    = min(max(w - 1, 0), WW - 4);
    const int dshift = (w - 1) - wlo;
#pragma unroll
    for (int s = t; s < 768; s += 256) {               // (ci, ni, hr)
        int ci = s / 24;
        int r  = s % 24;
        int ni = r / 3, hr = r % 3;
        int hh = h - 1 + hr;
        bool hok = (hh >= 0) && (hh < HH);
        const float* rowp = x + ((((b * 32 + ci) * 8 + ni) * HH + (hok ? hh : 0)) * WW) + wlo;
        f32x4u f4 = *(const f32x4u*)rowp;
        int kb = hr * 24 + ni;
#pragma unroll
        for (int kw = 0; kw < 3; ++kw) {
            int ww = w - 1 + kw;
            int j  = kw + dshift;
            float v = 0.f;
            if (hok && ww >= 0 && ww < WW)
                v = (j == 0) ? f4.x : (j == 1) ? f4.y : (j == 2) ? f4.z : f4.w;
            __bf16 hi = (__bf16)v;
            A_hi[ci * 96 + kb + kw * 8] = hi;
            A_lo[ci * 96 + kb + kw * 8] = (__bf16)(v - (float)hi);
        }
    }
    __syncthreads();                                    // (1) stage -> conv

    // ---- conv via MFMA: votes = Ah*Bh + Al*Bh + Ah*Bl (M=32, N=256, K=96) ----
    const __bf16* Bh = bp;
    const __bf16* Bl = bp + 24576;
    f32x4 acc[4][2];
#pragma unroll
    for (int i = 0; i < 4; ++i)
#pragma unroll
        for (int m = 0; m < 2; ++m) acc[i][m] = (f32x4){0.f, 0.f, 0.f, 0.f};

#pragma unroll
    for (int kst = 0; kst < 3; ++kst) {
        const int kb = kst * 32 + lg * 8;
        bf16x8 a_h0 = *(const bf16x8*)&A_hi[lr * 96 + kb];
        bf16x8 a_h1 = *(const bf16x8*)&A_hi[(16 + lr) * 96 + kb];
        bf16x8 a_l0 = *(const bf16x8*)&A_lo[lr * 96 + kb];
        bf16x8 a_l1 = *(const bf16x8*)&A_lo[(16 + lr) * 96 + kb];
#pragma unroll
        for (int i = 0; i < 4; ++i) {
            const int oc = (wv * 4 + i) * 16 + lr;
            bf16x8 bh = *(const bf16x8*)&Bh[oc * 96 + kb];
            bf16x8 bl = *(const bf16x8*)&Bl[oc * 96 + kb];
            acc[i][0] = __builtin_amdgcn_mfma_f32_16x16x32_bf16(a_h0, bh, acc[i][0], 0, 0, 0);
            acc[i][1] = __builtin_amdgcn_mfma_f32_16x16x32_bf16(a_h1, bh, acc[i][1], 0, 0, 0);
            acc[i][0] = __builtin_amdgcn_mfma_f32_16x16x32_bf16(a_l0, bh, acc[i][0], 0, 0, 0);
            acc[i][1] = __builtin_amdgcn_mfma_f32_16x16x32_bf16(a_l1, bh, acc[i][1], 0, 0, 0);
            acc[i][0] = __builtin_amdgcn_mfma_f32_16x16x32_bf16(a_h0, bl, acc[i][0], 0, 0, 0);
            acc[i][1] = __builtin_amdgcn_mfma_f32_16x16x32_bf16(a_h1, bl, acc[i][1], 0, 0, 0);
        }
    }
    __syncthreads();                                    // (2) A dead -> wave bufs

    // ---- wave-local transpose: no internal barriers (same-wave LDS order) ----
    float* buf = Rf + wv * 1152;                        // f32[32][36]
    float vcol[32];                                     // votes[ci][oc=t]
    f32x4 vr[4][2];                                     // votes[no*4+q][co*8 .. +7]
    const int sub  = (t >> 5) & 1;
    const int colr = t & 31;
    const int c8   = ((t >> 3) & 3) * 8;

#pragma unroll
    for (int i = 0; i < 2; ++i)
#pragma unroll
        for (int m = 0; m < 2; ++m)
#pragma unroll
            for (int r = 0; r < 4; ++r)
                buf[(m * 16 + lg * 4 + r) * 36 + i * 16 + lr] = acc[i][m][r];
    if (sub == 0) {
#pragma unroll
        for (int ci = 0; ci < 32; ++ci) vcol[ci] = buf[ci * 36 + colr];
#pragma unroll
        for (int q = 0; q < 4; ++q) {
            int ci = (t & 7) * 4 + q;
            vr[q][0] = *(const f32x4*)&buf[ci * 36 + c8];
            vr[q][1] = *(const f32x4*)&buf[ci * 36 + c8 + 4];
        }
    }
#pragma unroll
    for (int i = 2; i < 4; ++i)
#pragma unroll
        for (int m = 0; m < 2; ++m)
#pragma unroll
            for (int r = 0; r < 4; ++r)
                buf[(m * 16 + lg * 4 + r) * 36 + (i - 2) * 16 + lr] = acc[i][m][r];
    if (sub == 1) {
#pragma unroll
        for (int ci = 0; ci < 32; ++ci) vcol[ci] = buf[ci * 36 + colr];
#pragma unroll
        for (int q = 0; q < 4; ++q) {
            int ci = (t & 7) * 4 + q;
            vr[q][0] = *(const f32x4*)&buf[ci * 36 + c8];
            vr[q][1] = *(const f32x4*)&buf[ci * 36 + c8 + 4];
        }
    }
    __syncthreads();                                    // (3) bufs dead -> routing region

    // ---- routing: thread owns oc=t (co=t>>3, no=t&7) ----
    const int co = t >> 3;
    const int no = t & 7;
    const float bsv = bias[t];
    float dlog[4];
    float act;

    // iter 1: route uniform (softmax of zeros)
    {
        float p = 0.f;
#pragma unroll
        for (int ci = 0; ci < 32; ++ci) p += vcol[ci];
        p = fmaf(p, 0.03125f, bsv);
        float n2 = p * p;
        n2 += __shfl_xor(n2, 1); n2 += __shfl_xor(n2, 2); n2 += __shfl_xor(n2, 4);
        act = p * (n2 / ((1.f + n2) * sqrtf(n2 + 1e-9f)));
        act_lds[t] = act;
    }
    __syncthreads();                                    // (4) act visible
    {
        f32x4 a0 = *(const f32x4*)&act_lds[co * 8];
        f32x4 a1 = *(const f32x4*)&act_lds[co * 8 + 4];
#pragma unroll
        for (int q = 0; q < 4; ++q) {
            f32x4 v0 = vr[q][0], v1 = vr[q][1];
            float d = v0.x * a0.x + v0.y * a0.y + v0.z * a0.z + v0.w * a0.w
                    + v1.x * a1.x + v1.y * a1.y + v1.z * a1.z + v1.w * a1.w;
            dlog[q] = d;
            logits[no * 4 + q][co] = d;
        }
    }
    __syncthreads();                                    // (5) logits -> softmax

    // iters 2..3
#pragma unroll
    for (int it = 1; it < 3; ++it) {
        {
            float l0 = logits[co][no],      l1 = logits[co][no + 8];
            float l2 = logits[co][no + 16], l3 = logits[co][no + 24];
            float m = fmaxf(fmaxf(l0, l1), fmaxf(l2, l3));
            m = fmaxf(m, __shfl_xor(m, 1)); m = fmaxf(m, __shfl_xor(m, 2)); m = fmaxf(m, __shfl_xor(m, 4));
            float e0 = __expf(l0 - m), e1 = __expf(l1 - m);
            float e2 = __expf(l2 - m), e3 = __expf(l3 - m);
            float s = e0 + e1 + e2 + e3;
            s += __shfl_xor(s, 1); s += __shfl_xor(s, 2); s += __shfl_xor(s, 4);
            float inv = 1.f / s;
            route_T[no][co]      = e0 * inv;
            route_T[no + 8][co]  = e1 * inv;
            route_T[no + 16][co] = e2 * inv;
            route_T[no + 24][co] = e3 * inv;
        }
        __syncthreads();                                // (6/9) route -> preact

        float p = bsv;
#pragma unroll
        for (int j = 0; j < 8; ++j) {
            f32x4 rv = *(const f32x4*)&route_T[co][j * 4];
            p = fmaf(rv.x, vcol[j * 4 + 0], p);
            p = fmaf(rv.y, vcol[j * 4 + 1], p);
            p = fmaf(rv.z, vcol[j * 4 + 2], p);
            p = fmaf(rv.w, vcol[j * 4 + 3], p);
        }
        float n2 = p * p;
        n2 += __shfl_xor(n2, 1); n2 += __shfl_xor(n2, 2); n2 += __shfl_xor(n2, 4);
        act = p * (n2 / ((1.f + n2) * sqrtf(n2 + 1e-9f)));

        if (it == 1) {
            act_lds[t] = act;
            __syncthreads();                            // (7) act visible
            f32x4 a0 = *(const f32x4*)&act_lds[co * 8];
            f32x4 a1 = *(const f32x4*)&act_lds[co * 8 + 4];
#pragma unroll
            for (int q = 0; q < 4; ++q) {
                f32x4 v0 = vr[q][0], v1 = vr[q][1];
                float d = v0.x * a0.x + v0.y * a0.y + v0.z * a0.z + v0.w * a0.w
                        + v1.x * a1.x + v1.y * a1.y + v1.z * a1.z + v1.w * a1.w;
                dlog[q] += d;
                logits[no * 4 + q][co] = dlog[q];
            }
            __syncthreads();                            // (8) logits -> softmax
        }
    }

    // ---- out[b][oc=t][h][w] ----
    out[(b * 256 + t) * 400 + h * 20 + w] = act;
}

extern "C" void kernel_launch(void* const* d_in, const int* in_sizes, int n_in,
                              void* d_out, int out_size, void* d_ws, size_t ws_size,
                              hipStream_t stream) {
    const float* x    = (const float*)d_in[0];
    const float* Wt   = (const float*)d_in[1];
    const float* bias = (const float*)d_in[2];
    float* out        = (float*)d_out;
    __bf16* bp        = (__bf16*)d_ws;

    prepack_w_kernel<<<dim3(96), dim3(256), 0, stream>>>(Wt, bp);
    caps_mfma3_kernel<<<dim3(16 * HH * WW), dim3(256), 0, stream>>>(x, bp, bias, out);
}